// Round 5
// baseline (218.146 us; speedup 1.0000x reference)
//
#include <hip/hip_runtime.h>
#include <hip/hip_bf16.h>

#define B_ 8
#define L_ 2048
#define D_ 128
#define SCALE 0.08838834764831845f  // 1/sqrt(128)

typedef __attribute__((ext_vector_type(8))) short short8;  // 8 bf16 = 4 VGPR (MFMA A/B frag)
typedef __attribute__((ext_vector_type(4))) short s16x4;   // 4 bf16 = 8B LDS write
typedef __attribute__((ext_vector_type(4))) float f32x4;   // MFMA C/D frag

// Device-global scratch (fully rewritten every call).
__device__ float          g_lpart[2 * B_ * L_];        // rowsum partials [jhalf][b*L+i]
__device__ unsigned short g_vT[(size_t)B_ * D_ * L_];  // v^T bf16, layout [b][i/32][d][i%32]
__device__ unsigned short g_qb[(size_t)B_ * L_ * D_];  // q as bf16 rows
__device__ unsigned short g_vb[(size_t)B_ * L_ * D_];  // v as bf16 rows

static __device__ __forceinline__ float4 ld4(const float* p) { return *(const float4*)p; }
static __device__ __forceinline__ short bf(float f) {
    union { __hip_bfloat16 h; short s; } u; u.h = __float2bfloat16(f); return u.s;
}
static __device__ __forceinline__ short8 pack8(float4 a, float4 b) {
    short8 r;
    r[0] = bf(a.x); r[1] = bf(a.y); r[2] = bf(a.z); r[3] = bf(a.w);
    r[4] = bf(b.x); r[5] = bf(b.y); r[6] = bf(b.z); r[7] = bf(b.w);
    return r;
}
static __device__ __forceinline__ f32x4 mfma16(short8 a, short8 b, f32x4 c) {
    return __builtin_amdgcn_mfma_f32_16x16x32_bf16(a, b, c, 0, 0, 0);
}

// Raw barrier: drain LDS ops only (NOT vmcnt) so global stores/loads pipeline
// across iterations. sched_barrier(0) stops hoisting past the wait (rule #18).
#define BAR() do { asm volatile("s_waitcnt lgkmcnt(0)" ::: "memory"); \
                   __builtin_amdgcn_s_barrier();                      \
                   __builtin_amdgcn_sched_barrier(0); } while (0)

// Kc: q -> g_qb bf16 rows. 1024 blocks x 256 thr, 8 floats/thread.
__global__ __launch_bounds__(256) void cvt_q_kernel(const float* __restrict__ q) {
    const size_t idx = ((size_t)blockIdx.x * 256 + threadIdx.x) * 8;
    *(short8*)(void*)(g_qb + idx) = pack8(ld4(q + idx), ld4(q + idx + 4));
}

// K0: v -> g_vT ([b][i/32][d][i%32]) AND g_vb (bf16 rows). 256 blocks x 256 thr.
__global__ __launch_bounds__(256) void vT_kernel(const float* __restrict__ v) {
    __shared__ float t[64 * 132];  // [i][d], pitch 132
    const int tid = threadIdx.x;
    const int b = blockIdx.x >> 5, i0 = (blockIdx.x & 31) * 64;
    const float* vb = v + ((size_t)b * L_ + i0) * D_;
    #pragma unroll
    for (int c = 0; c < 8; ++c) {
        const int g = c * 256 + tid, row = g >> 5, c4 = (g & 31) * 4;
        *(float4*)(t + row * 132 + c4) = ld4(vb + (size_t)row * D_ + c4);
    }
    __syncthreads();
    #pragma unroll
    for (int c = 0; c < 4; ++c) {  // transposed store, [b][ic][d][ioff]
        const int g = c * 256 + tid, d = g >> 3, i8 = (g & 7) * 8;
        short8 r;
        #pragma unroll
        for (int j = 0; j < 8; ++j) r[j] = bf(t[(i8 + j) * 132 + d]);
        const int ic = (i0 + i8) >> 5, ioff = (i0 + i8) & 31;
        *(short8*)(void*)(g_vT + (((size_t)b * 64 + ic) * 128 + d) * 32 + ioff) = r;
    }
    #pragma unroll
    for (int c = 0; c < 4; ++c) {  // row-major bf16 rows from same staged tile
        const int g = c * 256 + tid, row = g >> 4, cc = g & 15;
        short8 r;
        #pragma unroll
        for (int j = 0; j < 8; ++j) r[j] = bf(t[row * 132 + cc * 8 + j]);
        *(short8*)(void*)(g_vb + ((size_t)b * L_ + i0 + row) * D_ + cc * 8) = r;
    }
}

// Pass A: row sums l[i].  Grid b(&7) x 32 it x 2 jh = 512.  Reg-staged double
// buffer: global loads for tile t+1 stay in flight across the raw barrier.
__global__ __launch_bounds__(256) void lsum_kernel() {
    __shared__ short vs[2][64 * 128];  // bf16 v rows, 16B-chunk XOR swizzle
    const int tid = threadIdx.x;
    const int b = blockIdx.x & 7, rest = blockIdx.x >> 3;
    const int it = rest & 31, jh = rest >> 5;
    const int i0 = it * 64;
    const int w = tid >> 6, lid = tid & 63, n16 = lid & 15, quad = lid >> 4;
    const int r8 = n16 & 7;
    const int srow = tid >> 4, scc = tid & 15;

    short8 qa[4];
    const unsigned short* qrow = g_qb + ((size_t)b * L_ + i0 + w * 16 + n16) * D_ + quad * 8;
    #pragma unroll
    for (int c = 0; c < 4; ++c) qa[c] = *(const short8*)(qrow + c * 32);

    const unsigned short* vbp = g_vb + ((size_t)b * L_ + (size_t)jh * 1024) * D_;
    short8 R[4];
    #pragma unroll
    for (int c = 0; c < 4; ++c) {  // prologue: load jt=0 tile to regs
        const int row = srow + c * 16;
        R[c] = *(const short8*)(vbp + (size_t)row * D_ + scc * 8);
    }

    float racc[4] = {0.f, 0.f, 0.f, 0.f};
    #pragma unroll
    for (int jt = 0; jt < 16; ++jt) {
        short* vsp = vs[jt & 1];
        #pragma unroll
        for (int c = 0; c < 4; ++c) {  // regs -> LDS (swizzled)
            const int row = srow + c * 16;
            *(short8*)(&vsp[row * 128 + ((scc ^ (row & 7)) * 8)]) = R[c];
        }
        if (jt < 15) {  // prefetch next tile to regs (crosses the barrier)
            const unsigned short* src = vbp + (size_t)(jt + 1) * 64 * D_;
            #pragma unroll
            for (int c = 0; c < 4; ++c) {
                const int row = srow + c * 16;
                R[c] = *(const short8*)(src + (size_t)row * D_ + scc * 8);
            }
        }
        BAR();
        #pragma unroll
        for (int jc = 0; jc < 4; ++jc) {
            f32x4 d = {0.f, 0.f, 0.f, 0.f};
            #pragma unroll
            for (int c = 0; c < 4; ++c) {
                const short8 vf = *(const short8*)(
                    &vsp[(jc * 16 + n16) * 128 + (((c * 4 + quad) ^ r8) * 8)]);
                d = mfma16(qa[c], vf, d);
            }
            #pragma unroll
            for (int r = 0; r < 4; ++r) racc[r] += __expf(d[r] * SCALE);
        }
    }
    #pragma unroll
    for (int m = 1; m <= 8; m <<= 1)
        #pragma unroll
        for (int r = 0; r < 4; ++r) racc[r] += __shfl_xor(racc[r], m, 64);
    if (n16 == 0) {
        *(float4*)(g_lpart + jh * (B_ * L_) + b * L_ + i0 + w * 16 + quad * 4) =
            make_float4(racc[0], racc[1], racc[2], racc[3]);
    }
}

// Pass B v5: BJ=32 -> grid 8b x 64 slabs = 512 blocks (2/CU for overlap),
// 256 thr (4 waves). i-tile 128/iter (wave owns 32 rows = 2 m-tiles), 16 iters,
// ONE raw barrier/iter, dbuf eF+aT (LDS 56KB). vf B-frags direct from g_vT.
__global__ __launch_bounds__(256) void fused_kernel(float* __restrict__ attn,
                                                    float* __restrict__ out) {
    __shared__ short vj[32 * 128];     // v rows j0..j0+31 [j][k], swizzled (8KB)
    __shared__ float eF[2][128 * 32];  // fp32 e [i][j], rotated (32KB)
    __shared__ short aT[2][32 * 128];  // bf16 attn^T [j][i], granule-XOR (16KB)
    const int tid = threadIdx.x;
    const int b = blockIdx.x & 7, j0 = (blockIdx.x >> 3) * 32;
    const int w = tid >> 6, lid = tid & 63, n16 = lid & 15, quad = lid >> 4;
    const int r8 = n16 & 7;
    float* ab = attn + (size_t)b * L_ * L_;
    const unsigned short* vT2b = g_vT + (size_t)b * D_ * L_;
    const unsigned short* qbb = g_qb + (size_t)b * L_ * D_;
    const unsigned short* vbp = g_vb + (size_t)b * L_ * D_;
    const float* lp0 = g_lpart + (size_t)b * L_;
    const float* lp1 = g_lpart + (size_t)(B_ * L_) + (size_t)b * L_;

    #pragma unroll
    for (int c = 0; c < 2; ++c) {  // stage vj once: 512 chunks of 16B
        const int g = c * 256 + tid, row = g >> 4, cc = g & 15;
        *(short8*)(&vj[row * 128 + ((cc ^ (row & 7)) * 8)]) =
            *(const short8*)(vbp + (size_t)(j0 + row) * D_ + cc * 8);
    }
    // prefetch t=0 q-frags (2 m-tiles) + l-partials
    short8 qa[2][4];
    #pragma unroll
    for (int m = 0; m < 2; ++m) {
        const unsigned short* q0 = qbb + (size_t)(w * 32 + m * 16 + n16) * D_ + quad * 8;
        #pragma unroll
        for (int c = 0; c < 4; ++c) qa[m][c] = *(const short8*)(q0 + c * 32);
    }
    float4 s0[2], s1[2];
    #pragma unroll
    for (int m = 0; m < 2; ++m) {
        s0[m] = ld4(lp0 + w * 32 + m * 16 + quad * 4);
        s1[m] = ld4(lp1 + w * 32 + m * 16 + quad * 4);
    }

    f32x4 oacc[2][2];  // [jc][dc]
    #pragma unroll
    for (int jc = 0; jc < 2; ++jc)
        #pragma unroll
        for (int dc = 0; dc < 2; ++dc) oacc[jc][dc] = (f32x4){0.f, 0.f, 0.f, 0.f};
    __syncthreads();  // vj ready

    for (int t = 0; t < 16; ++t) {
        const int i0 = t * 128;
        float* eFp = eF[t & 1];
        short* aTp = aT[t & 1];
        // PV B-frags first (in flight through phase1): [ks][dc], coalesced 1KB
        short8 vfr[4][2];
        #pragma unroll
        for (int ks = 0; ks < 4; ++ks)
            #pragma unroll
            for (int dc = 0; dc < 2; ++dc)
                vfr[ks][dc] = *(const short8*)(
                    vT2b + ((size_t)(t * 4 + ks) * 128 + (w * 32 + dc * 16 + n16)) * 32 +
                    quad * 8);
        // QK: wave rows [i0+w*32, +32) x 32 j
        f32x4 dj[2][2];
        #pragma unroll
        for (int m = 0; m < 2; ++m)
            #pragma unroll
            for (int jc = 0; jc < 2; ++jc) dj[m][jc] = (f32x4){0.f, 0.f, 0.f, 0.f};
        #pragma unroll
        for (int c = 0; c < 4; ++c)
            #pragma unroll
            for (int jc = 0; jc < 2; ++jc) {
                const short8 vf = *(const short8*)(
                    &vj[(jc * 16 + n16) * 128 + (((c * 4 + quad) ^ r8) * 8)]);
                #pragma unroll
                for (int m = 0; m < 2; ++m) dj[m][jc] = mfma16(qa[m][c], vf, dj[m][jc]);
            }
        float linv[2][4];
        #pragma unroll
        for (int m = 0; m < 2; ++m) {
            linv[m][0] = 1.0f / (s0[m].x + s1[m].x);
            linv[m][1] = 1.0f / (s0[m].y + s1[m].y);
            linv[m][2] = 1.0f / (s0[m].z + s1[m].z);
            linv[m][3] = 1.0f / (s0[m].w + s1[m].w);
        }
        if (t < 15) {  // prefetch next iter q-frags + l-partials (hidden by PV)
            #pragma unroll
            for (int m = 0; m < 2; ++m) {
                const unsigned short* qn =
                    qbb + (size_t)(i0 + 128 + w * 32 + m * 16 + n16) * D_ + quad * 8;
                #pragma unroll
                for (int c = 0; c < 4; ++c) qa[m][c] = *(const short8*)(qn + c * 32);
                s0[m] = ld4(lp0 + i0 + 128 + w * 32 + m * 16 + quad * 4);
                s1[m] = ld4(lp1 + i0 + 128 + w * 32 + m * 16 + quad * 4);
            }
        }
        // e -> eF (fp32 [il][j], rotate j by (il&7)*4) + aT (bf16 [j][il], 16B-granule^j&7)
        #pragma unroll
        for (int m = 0; m < 2; ++m) {
            const int ilb = w * 32 + m * 16 + quad * 4;          // + r
            const int gran = w * 4 + m * 2 + (quad >> 1);        // 16B granule of il
            #pragma unroll
            for (int jc = 0; jc < 2; ++jc) {
                const int j = jc * 16 + n16;
                s16x4 aw;
                #pragma unroll
                for (int r = 0; r < 4; ++r) {
                    const float e = __expf(dj[m][jc][r] * SCALE) * linv[m][r];
                    eFp[(ilb + r) * 32 + ((j + ((ilb + r) & 7) * 4) & 31)] = e;
                    aw[r] = bf(e);
                }
                *(s16x4*)(&aTp[j * 128 + ((gran ^ r8) * 8) + (quad & 1) * 4]) = aw;
            }
        }
        BAR();
        // attn stores: per instr 8 rows x 128B contiguous, nontemporal
        #pragma unroll
        for (int c = 0; c < 4; ++c) {
            const int g = c * 256 + tid, row = g >> 3, j4 = g & 7;
            const int jj = ((j4 + (row & 7)) & 7) * 4;
            const f32x4 tv = *(const f32x4*)(&eFp[row * 32 + jj]);
            __builtin_nontemporal_store(
                tv, (f32x4*)(ab + (size_t)(i0 + row) * L_ + j0 + j4 * 4));
        }
        // PV: out[j][d] += attn^T[j][i] v[i][d]
        __builtin_amdgcn_s_setprio(1);
        #pragma unroll
        for (int ks = 0; ks < 4; ++ks)
            #pragma unroll
            for (int jc = 0; jc < 2; ++jc) {
                const short8 af = *(const short8*)(
                    &aTp[(jc * 16 + n16) * 128 + (((ks * 4 + quad) ^ r8) * 8)]);
                #pragma unroll
                for (int dc = 0; dc < 2; ++dc)
                    oacc[jc][dc] = mfma16(af, vfr[ks][dc], oacc[jc][dc]);
            }
        __builtin_amdgcn_s_setprio(0);
    }
    // D[row=j0+jc*16+quad*4+r][col=w*32+dc*16+n16]
    #pragma unroll
    for (int jc = 0; jc < 2; ++jc)
        #pragma unroll
        for (int dc = 0; dc < 2; ++dc)
            #pragma unroll
            for (int r = 0; r < 4; ++r)
                __builtin_nontemporal_store(
                    oacc[jc][dc][r],
                    out + ((size_t)b * L_ + j0 + jc * 16 + quad * 4 + r) * D_ +
                        w * 32 + dc * 16 + n16);
}

extern "C" void kernel_launch(void* const* d_in, const int* in_sizes, int n_in,
                              void* d_out, int out_size, void* d_ws, size_t ws_size,
                              hipStream_t stream) {
    const float* q = (const float*)d_in[0];
    // d_in[1] = k: unused by the reference (scores come from q and v).
    const float* v = (const float*)d_in[2];
    float* out  = (float*)d_out;
    float* attn = out + (size_t)B_ * L_ * D_;  // outputs concatenated: [out | attn]

    cvt_q_kernel<<<dim3(1024), 256, 0, stream>>>(q);
    vT_kernel<<<dim3(B_ * 32), 256, 0, stream>>>(v);
    lsum_kernel<<<dim3(B_ * 64), 256, 0, stream>>>();
    fused_kernel<<<dim3(B_ * 64), 256, 0, stream>>>(attn, out);

    (void)in_sizes; (void)n_in; (void)out_size; (void)d_ws; (void)ws_size;
}

// Round 6
// 199.480 us; speedup vs baseline: 1.0936x; 1.0936x over previous
//
#include <hip/hip_runtime.h>
#include <hip/hip_bf16.h>

#define B_ 8
#define L_ 2048
#define D_ 128
#define SCALE 0.08838834764831845f  // 1/sqrt(128)

typedef __attribute__((ext_vector_type(8))) short short8;  // 8 bf16 = 4 VGPR (MFMA A/B frag)
typedef __attribute__((ext_vector_type(4))) short s16x4;   // 4 bf16 = 8B LDS write
typedef __attribute__((ext_vector_type(4))) float f32x4;   // MFMA C/D frag

// Device-global scratch (fully rewritten every call).
__device__ float          g_lpart[2 * B_ * L_];        // rowsum partials [jhalf][b*L+i]
__device__ unsigned short g_vT[(size_t)B_ * D_ * L_];  // v^T bf16, layout [b][i/32][d][i%32]
__device__ unsigned short g_qb[(size_t)B_ * L_ * D_];  // q as bf16 rows
__device__ unsigned short g_vb[(size_t)B_ * L_ * D_];  // v as bf16 rows

static __device__ __forceinline__ float4 ld4(const float* p) { return *(const float4*)p; }
static __device__ __forceinline__ short bf(float f) {
    union { __hip_bfloat16 h; short s; } u; u.h = __float2bfloat16(f); return u.s;
}
static __device__ __forceinline__ short8 pack8(float4 a, float4 b) {
    short8 r;
    r[0] = bf(a.x); r[1] = bf(a.y); r[2] = bf(a.z); r[3] = bf(a.w);
    r[4] = bf(b.x); r[5] = bf(b.y); r[6] = bf(b.z); r[7] = bf(b.w);
    return r;
}
static __device__ __forceinline__ f32x4 mfma16(short8 a, short8 b, f32x4 c) {
    return __builtin_amdgcn_mfma_f32_16x16x32_bf16(a, b, c, 0, 0, 0);
}

// Raw barrier: drain LDS ops only (NOT vmcnt) so global stores/loads pipeline
// across iterations. sched_barrier(0) stops hoisting past the wait (rule #18).
#define BAR() do { asm volatile("s_waitcnt lgkmcnt(0)" ::: "memory"); \
                   __builtin_amdgcn_s_barrier();                      \
                   __builtin_amdgcn_sched_barrier(0); } while (0)

// Kc: q -> g_qb bf16 rows. 1024 blocks x 256 thr, 8 floats/thread.
__global__ __launch_bounds__(256) void cvt_q_kernel(const float* __restrict__ q) {
    const size_t idx = ((size_t)blockIdx.x * 256 + threadIdx.x) * 8;
    *(short8*)(void*)(g_qb + idx) = pack8(ld4(q + idx), ld4(q + idx + 4));
}

// K0: v -> g_vT ([b][i/32][d][i%32]) AND g_vb (bf16 rows). 256 blocks x 256 thr.
__global__ __launch_bounds__(256) void vT_kernel(const float* __restrict__ v) {
    __shared__ float t[64 * 132];  // [i][d], pitch 132
    const int tid = threadIdx.x;
    const int b = blockIdx.x >> 5, i0 = (blockIdx.x & 31) * 64;
    const float* vb = v + ((size_t)b * L_ + i0) * D_;
    #pragma unroll
    for (int c = 0; c < 8; ++c) {
        const int g = c * 256 + tid, row = g >> 5, c4 = (g & 31) * 4;
        *(float4*)(t + row * 132 + c4) = ld4(vb + (size_t)row * D_ + c4);
    }
    __syncthreads();
    #pragma unroll
    for (int c = 0; c < 4; ++c) {  // transposed store, [b][ic][d][ioff]
        const int g = c * 256 + tid, d = g >> 3, i8 = (g & 7) * 8;
        short8 r;
        #pragma unroll
        for (int j = 0; j < 8; ++j) r[j] = bf(t[(i8 + j) * 132 + d]);
        const int ic = (i0 + i8) >> 5, ioff = (i0 + i8) & 31;
        *(short8*)(void*)(g_vT + (((size_t)b * 64 + ic) * 128 + d) * 32 + ioff) = r;
    }
    #pragma unroll
    for (int c = 0; c < 4; ++c) {  // row-major bf16 rows from same staged tile
        const int g = c * 256 + tid, row = g >> 4, cc = g & 15;
        short8 r;
        #pragma unroll
        for (int j = 0; j < 8; ++j) r[j] = bf(t[row * 132 + cc * 8 + j]);
        *(short8*)(void*)(g_vb + ((size_t)b * L_ + i0 + row) * D_ + cc * 8) = r;
    }
}

// Pass A: row sums l[i].  Grid b(&7) x 32 it x 2 jh = 512.  Reg-staged double
// buffer: global loads for tile t+1 stay in flight across the raw barrier.
__global__ __launch_bounds__(256) void lsum_kernel() {
    __shared__ short vs[2][64 * 128];  // bf16 v rows, 16B-chunk XOR swizzle
    const int tid = threadIdx.x;
    const int b = blockIdx.x & 7, rest = blockIdx.x >> 3;
    const int it = rest & 31, jh = rest >> 5;
    const int i0 = it * 64;
    const int w = tid >> 6, lid = tid & 63, n16 = lid & 15, quad = lid >> 4;
    const int r8 = n16 & 7;
    const int srow = tid >> 4, scc = tid & 15;

    short8 qa[4];
    const unsigned short* qrow = g_qb + ((size_t)b * L_ + i0 + w * 16 + n16) * D_ + quad * 8;
    #pragma unroll
    for (int c = 0; c < 4; ++c) qa[c] = *(const short8*)(qrow + c * 32);

    const unsigned short* vbp = g_vb + ((size_t)b * L_ + (size_t)jh * 1024) * D_;
    short8 R[4];
    #pragma unroll
    for (int c = 0; c < 4; ++c) {  // prologue: load jt=0 tile to regs
        const int row = srow + c * 16;
        R[c] = *(const short8*)(vbp + (size_t)row * D_ + scc * 8);
    }

    float racc[4] = {0.f, 0.f, 0.f, 0.f};
    #pragma unroll
    for (int jt = 0; jt < 16; ++jt) {
        short* vsp = vs[jt & 1];
        #pragma unroll
        for (int c = 0; c < 4; ++c) {  // regs -> LDS (swizzled)
            const int row = srow + c * 16;
            *(short8*)(&vsp[row * 128 + ((scc ^ (row & 7)) * 8)]) = R[c];
        }
        if (jt < 15) {  // prefetch next tile to regs (crosses the barrier)
            const unsigned short* src = vbp + (size_t)(jt + 1) * 64 * D_;
            #pragma unroll
            for (int c = 0; c < 4; ++c) {
                const int row = srow + c * 16;
                R[c] = *(const short8*)(src + (size_t)row * D_ + scc * 8);
            }
        }
        BAR();
        #pragma unroll
        for (int jc = 0; jc < 4; ++jc) {
            f32x4 d = {0.f, 0.f, 0.f, 0.f};
            #pragma unroll
            for (int c = 0; c < 4; ++c) {
                const short8 vf = *(const short8*)(
                    &vsp[(jc * 16 + n16) * 128 + (((c * 4 + quad) ^ r8) * 8)]);
                d = mfma16(qa[c], vf, d);
            }
            #pragma unroll
            for (int r = 0; r < 4; ++r) racc[r] += __expf(d[r] * SCALE);
        }
    }
    #pragma unroll
    for (int m = 1; m <= 8; m <<= 1)
        #pragma unroll
        for (int r = 0; r < 4; ++r) racc[r] += __shfl_xor(racc[r], m, 64);
    if (n16 == 0) {
        *(float4*)(g_lpart + jh * (B_ * L_) + b * L_ + i0 + w * 16 + quad * 4) =
            make_float4(racc[0], racc[1], racc[2], racc[3]);
    }
}

// Pass B v6 = R4 geometry (BJ=64, 512 thr, 8 waves, 256 blocks, 112KB LDS)
// + vfr register double-buffer: iter t+1's PV B-frag loads are issued BEFORE
// iter t's attn stores, so the (in-order) vmcnt waits for them never require
// store retirement -> stores throttle via BW only, not latency coupling.
__global__ __launch_bounds__(512) void fused_kernel(float* __restrict__ attn,
                                                    float* __restrict__ out) {
    __shared__ short vj[64 * 128];     // v rows j0..j0+63 [j][k], swizzled (16KB)
    __shared__ float eF[2][128 * 64];  // fp32 e [i][j], chunk-swizzled (64KB)
    __shared__ short aT[2][64 * 128];  // bf16 attn^T [j][i], granule-swizzled (32KB)
    const int tid = threadIdx.x;
    const int b = blockIdx.x & 7, j0 = (blockIdx.x >> 3) * 64;
    const int w = tid >> 6, lid = tid & 63, n16 = lid & 15, quad = lid >> 4;
    const int r8 = n16 & 7;
    float* ab = attn + (size_t)b * L_ * L_;
    const unsigned short* vT2b = g_vT + (size_t)b * D_ * L_;
    const unsigned short* qbb = g_qb + (size_t)b * L_ * D_;
    const unsigned short* vbp = g_vb + (size_t)b * L_ * D_;
    const float* lp0 = g_lpart + (size_t)b * L_;
    const float* lp1 = g_lpart + (size_t)(B_ * L_) + (size_t)b * L_;

    #pragma unroll
    for (int c = 0; c < 2; ++c) {  // stage vj once: 1024 chunks of 16B
        const int g = c * 512 + tid, row = g >> 4, cc = g & 15;
        *(short8*)(&vj[row * 128 + ((cc ^ (row & 7)) * 8)]) =
            *(const short8*)(vbp + (size_t)(j0 + row) * D_ + cc * 8);
    }
    short8 qa[4];
    {
        const unsigned short* q0 = qbb + (size_t)(w * 16 + n16) * D_ + quad * 8;
        #pragma unroll
        for (int c = 0; c < 4; ++c) qa[c] = *(const short8*)(q0 + c * 32);
    }
    float4 s0 = ld4(lp0 + w * 16 + quad * 4);
    float4 s1 = ld4(lp1 + w * 16 + quad * 4);
    // prologue: t=0 PV B-frags ([b][i/32][d][i%32]; coalesced 1KB per wave-load)
    short8 vfrP[4];
    #pragma unroll
    for (int ks = 0; ks < 4; ++ks)
        vfrP[ks] = *(const short8*)(
            vT2b + ((size_t)ks * 128 + (w * 16 + n16)) * 32 + quad * 8);

    f32x4 oacc[4];
    #pragma unroll
    for (int jc = 0; jc < 4; ++jc) oacc[jc] = (f32x4){0.f, 0.f, 0.f, 0.f};
    __syncthreads();  // vj ready

    for (int t = 0; t < 16; ++t) {
        const int i0 = t * 128;
        float* eFp = eF[t & 1];
        short* aTp = aT[t & 1];
        // QK: wave w rows i0+w*16..+15 x 64 j
        f32x4 dj[4];
        #pragma unroll
        for (int jc = 0; jc < 4; ++jc) {
            f32x4 d = {0.f, 0.f, 0.f, 0.f};
            #pragma unroll
            for (int c = 0; c < 4; ++c) {
                const short8 vf = *(const short8*)(
                    &vj[(jc * 16 + n16) * 128 + (((c * 4 + quad) ^ r8) * 8)]);
                d = mfma16(qa[c], vf, d);
            }
            dj[jc] = d;
        }
        const float linv[4] = {1.0f / (s0.x + s1.x), 1.0f / (s0.y + s1.y),
                               1.0f / (s0.z + s1.z), 1.0f / (s0.w + s1.w)};
        if (t < 15) {  // prefetch next iter q-frags + l-partials (before stores)
            const unsigned short* qn = qbb + (size_t)(i0 + 128 + w * 16 + n16) * D_ + quad * 8;
            #pragma unroll
            for (int c = 0; c < 4; ++c) qa[c] = *(const short8*)(qn + c * 32);
            s0 = ld4(lp0 + i0 + 128 + w * 16 + quad * 4);
            s1 = ld4(lp1 + i0 + 128 + w * 16 + quad * 4);
        }
        // e -> eF (fp32, chunk-swizzle) + aT (bf16 [j][i], granule-XOR)
        const int ilb = w * 16 + quad * 4;
        #pragma unroll
        for (int jc = 0; jc < 4; ++jc) {
            s16x4 aw;
            #pragma unroll
            for (int r = 0; r < 4; ++r) {
                const float e = __expf(dj[jc][r] * SCALE) * linv[r];
                eFp[(ilb + r) * 64 + ((jc ^ quad) * 16) + n16] = e;
                aw[r] = bf(e);
            }
            *(s16x4*)(&aTp[(jc * 16 + n16) * 128 +
                           (((w * 2 + (quad >> 1)) ^ r8) * 8) + (quad & 1) * 4]) = aw;
        }
        BAR();
        // vfr prefetch for t+1 — issued BEFORE this iter's stores (decoupling)
        short8 vfrN[4];
        if (t < 15) {
            #pragma unroll
            for (int ks = 0; ks < 4; ++ks)
                vfrN[ks] = *(const short8*)(
                    vT2b + ((size_t)((t + 1) * 4 + ks) * 128 + (w * 16 + n16)) * 32 +
                    quad * 8);
        }
        __builtin_amdgcn_sched_barrier(0);  // keep prefetch above the stores
        // attn stores: 4 rows x 256B contiguous per instruction, nontemporal
        #pragma unroll
        for (int c = 0; c < 4; ++c) {
            const int g = c * 512 + tid, row = g >> 4, j4 = g & 15;
            const int phys = (j4 >> 2) ^ ((row >> 2) & 3);
            const f32x4 tv = *(const f32x4*)(&eFp[row * 64 + phys * 16 + (g & 3) * 4]);
            __builtin_nontemporal_store(
                tv, (f32x4*)(ab + (size_t)(i0 + row) * L_ + j0 + j4 * 4));
        }
        __builtin_amdgcn_sched_barrier(0);  // keep stores above PV region
        // PV: out[j][d] += attn^T[j][i] v[i][d], using vfrP loaded LAST iter
        __builtin_amdgcn_s_setprio(1);
        #pragma unroll
        for (int ks = 0; ks < 4; ++ks)
            #pragma unroll
            for (int jc = 0; jc < 4; ++jc) {
                const short8 af = *(const short8*)(
                    &aTp[(jc * 16 + n16) * 128 + (((ks * 4 + quad) ^ r8) * 8)]);
                oacc[jc] = mfma16(af, vfrP[ks], oacc[jc]);
            }
        __builtin_amdgcn_s_setprio(0);
        #pragma unroll
        for (int ks = 0; ks < 4; ++ks) vfrP[ks] = vfrN[ks];
    }
    // D[row=j_local=jc*16+quad*4+r][col=d=w*16+n16]
    #pragma unroll
    for (int jc = 0; jc < 4; ++jc)
        #pragma unroll
        for (int r = 0; r < 4; ++r)
            __builtin_nontemporal_store(
                oacc[jc][r],
                out + ((size_t)b * L_ + j0 + jc * 16 + quad * 4 + r) * D_ + w * 16 + n16);
}

extern "C" void kernel_launch(void* const* d_in, const int* in_sizes, int n_in,
                              void* d_out, int out_size, void* d_ws, size_t ws_size,
                              hipStream_t stream) {
    const float* q = (const float*)d_in[0];
    // d_in[1] = k: unused by the reference (scores come from q and v).
    const float* v = (const float*)d_in[2];
    float* out  = (float*)d_out;
    float* attn = out + (size_t)B_ * L_ * D_;  // outputs concatenated: [out | attn]

    cvt_q_kernel<<<dim3(1024), 256, 0, stream>>>(q);
    vT_kernel<<<dim3(B_ * 32), 256, 0, stream>>>(v);
    lsum_kernel<<<dim3(B_ * 64), 256, 0, stream>>>();
    fused_kernel<<<dim3(B_ * 32), 512, 0, stream>>>(attn, out);

    (void)in_sizes; (void)n_in; (void)out_size; (void)d_ws; (void)ws_size;
}